// Round 1
// baseline (70.423 us; speedup 1.0000x reference)
//
#include <hip/hip_runtime.h>
#include <math.h>

// Problem constants (from reference)
#define B_     4
#define N_     1024
#define L_     150
#define VOCAB_ 5
#define EMB_   128
#define UNITS_ 64

// Key insight: reference takes outs[0] == hidden state after the FIRST LSTM
// step with h0=c0=0. So:
//   z      = emb_table[tok0] @ kernel + bias      (rec_kernel term is zero)
//   c1     = sigmoid(z_i) * tanh(z_g)             (f*c0 term is zero)
//   h1     = sigmoid(z_o) * tanh(c1)
// Only tokens[:, :, 0] is used, and vocab=5 -> only 5 distinct output rows.
// Precompute h_table[5][64] per block (tiny), then gather-write.

__global__ __launch_bounds__(256) void lstm_first_step_kernel(
    const int*   __restrict__ tokens,  // [B, N, L]
    const float* __restrict__ emb,     // [VOCAB, EMB]
    const float* __restrict__ kern,    // [EMB, 4*UNITS] gate order i,f,g,o
    const float* __restrict__ bias,    // [4*UNITS]
    float*       __restrict__ out)     // [B*N, UNITS]
{
    __shared__ float h_table[VOCAB_ * UNITS_];

    const int tid = threadIdx.x;

    // --- Stage 1: compute the 5x64 first-step LSTM output table (redundant per block) ---
    for (int idx = tid; idx < VOCAB_ * UNITS_; idx += blockDim.x) {
        const int v = idx / UNITS_;
        const int u = idx - v * UNITS_;
        float zi = bias[u];
        float zg = bias[2 * UNITS_ + u];
        float zo = bias[3 * UNITS_ + u];
        const float* ev = emb + v * EMB_;
        #pragma unroll 8
        for (int e = 0; e < EMB_; ++e) {
            const float a = ev[e];
            const float* kr = kern + e * (4 * UNITS_);
            zi = fmaf(a, kr[u],              zi);
            zg = fmaf(a, kr[2 * UNITS_ + u], zg);
            zo = fmaf(a, kr[3 * UNITS_ + u], zo);
        }
        const float ig = 1.0f / (1.0f + expf(-zi));
        const float g  = tanhf(zg);
        const float og = 1.0f / (1.0f + expf(-zo));
        const float c1 = ig * g;
        h_table[idx] = og * tanhf(c1);
    }
    __syncthreads();

    // --- Stage 2: gather-write. out[row] = h_table[tokens[row*L]], vectorized float4 ---
    const float4* ht4  = (const float4*)h_table;
    float4*       out4 = (float4*)out;
    const int total4 = B_ * N_ * (UNITS_ / 4);  // 65536 float4 elements

    for (int i = blockIdx.x * blockDim.x + tid; i < total4;
         i += gridDim.x * blockDim.x) {
        const int row = i >> 4;   // / (UNITS_/4)
        const int seg = i & 15;   // % (UNITS_/4)
        const int tok = tokens[row * L_];  // broadcast within 16-thread groups
        out4[i] = ht4[tok * (UNITS_ / 4) + seg];
    }
}

extern "C" void kernel_launch(void* const* d_in, const int* in_sizes, int n_in,
                              void* d_out, int out_size, void* d_ws, size_t ws_size,
                              hipStream_t stream) {
    const int*   tokens = (const int*)d_in[0];    // [4,1024,150] int32
    const float* emb    = (const float*)d_in[1];  // [5,128]
    const float* kern   = (const float*)d_in[2];  // [128,256]
    // d_in[3] = rec_kernel [64,256] -- unused (h0 = 0)
    const float* bias   = (const float*)d_in[4];  // [256]
    float* out = (float*)d_out;                   // [4,1024,1,64] fp32

    // 65536 float4 outputs -> exactly 256 blocks x 256 threads, one per thread.
    lstm_first_step_kernel<<<256, 256, 0, stream>>>(tokens, emb, kern, bias, out);
}

// Round 2
// 67.673 us; speedup vs baseline: 1.0406x; 1.0406x over previous
//
#include <hip/hip_runtime.h>
#include <math.h>

// Problem constants (from reference)
#define B_     4
#define N_     1024
#define L_     150
#define VOCAB_ 5
#define EMB_   128
#define UNITS_ 64

// Reference takes outs[0] == hidden state after the FIRST LSTM step with
// h0=c0=0:
//   z  = emb_table[tok0] @ kernel + bias   (rec_kernel term vanishes)
//   c1 = sigmoid(z_i) * tanh(z_g)          (f*c0 vanishes)
//   h1 = sigmoid(z_o) * tanh(c1)
// Only tokens[:, :, 0] matters; vocab=5 -> only 5 distinct output rows.
//
// R1: block=320 (one table entry per thread, 5 waves), float4 emb loads,
// grid=205 (exact cover of 65536 float4 outputs).

#define BLOCK_ 320
#define GRID_  205   // 205*320 = 65600 >= 65536 output float4s

__global__ __launch_bounds__(BLOCK_) void lstm_first_step_kernel(
    const int*   __restrict__ tokens,  // [B, N, L]
    const float* __restrict__ emb,     // [VOCAB, EMB]
    const float* __restrict__ kern,    // [EMB, 4*UNITS] gate order i,f,g,o
    const float* __restrict__ bias,    // [4*UNITS]
    float*       __restrict__ out)     // [B*N, UNITS]
{
    __shared__ float h_table[VOCAB_ * UNITS_];

    const int tid = threadIdx.x;       // 0..319, exactly one (v,u) per thread
    {
        const int v = tid >> 6;        // wave index == vocab id (wave-uniform)
        const int u = tid & 63;

        float zi = bias[u];
        float zg = bias[2 * UNITS_ + u];
        float zo = bias[3 * UNITS_ + u];

        const float4* ev4 = (const float4*)(emb + v * EMB_);
        const float*  kc  = kern + u;   // column base; rows stride 4*UNITS_

        #pragma unroll 8
        for (int e4 = 0; e4 < EMB_ / 4; ++e4) {
            const float4 a = ev4[e4];   // wave-broadcast load
            const float* k0 = kc + (4 * e4) * (4 * UNITS_);
            zi = fmaf(a.x, k0[0 * 256],              zi);
            zg = fmaf(a.x, k0[0 * 256 + 2 * UNITS_], zg);
            zo = fmaf(a.x, k0[0 * 256 + 3 * UNITS_], zo);
            zi = fmaf(a.y, k0[1 * 256],              zi);
            zg = fmaf(a.y, k0[1 * 256 + 2 * UNITS_], zg);
            zo = fmaf(a.y, k0[1 * 256 + 3 * UNITS_], zo);
            zi = fmaf(a.z, k0[2 * 256],              zi);
            zg = fmaf(a.z, k0[2 * 256 + 2 * UNITS_], zg);
            zo = fmaf(a.z, k0[2 * 256 + 3 * UNITS_], zo);
            zi = fmaf(a.w, k0[3 * 256],              zi);
            zg = fmaf(a.w, k0[3 * 256 + 2 * UNITS_], zg);
            zo = fmaf(a.w, k0[3 * 256 + 3 * UNITS_], zo);
        }

        const float ig = 1.0f / (1.0f + expf(-zi));
        const float g  = tanhf(zg);
        const float og = 1.0f / (1.0f + expf(-zo));
        h_table[tid] = og * tanhf(ig * g);
    }
    __syncthreads();

    // Gather-write: out[row] = h_table[tokens[row*L]], one float4 per thread.
    const float4* ht4  = (const float4*)h_table;
    float4*       out4 = (float4*)out;
    const int total4 = B_ * N_ * (UNITS_ / 4);  // 65536

    const int i = blockIdx.x * BLOCK_ + tid;
    if (i < total4) {
        const int row = i >> 4;   // / (UNITS_/4)
        const int seg = i & 15;   // % (UNITS_/4)
        const int tok = tokens[row * L_];  // broadcast within 16-thread groups
        out4[i] = ht4[tok * (UNITS_ / 4) + seg];
    }
}

extern "C" void kernel_launch(void* const* d_in, const int* in_sizes, int n_in,
                              void* d_out, int out_size, void* d_ws, size_t ws_size,
                              hipStream_t stream) {
    const int*   tokens = (const int*)d_in[0];    // [4,1024,150] int32
    const float* emb    = (const float*)d_in[1];  // [5,128]
    const float* kern   = (const float*)d_in[2];  // [128,256]
    // d_in[3] = rec_kernel [64,256] -- unused (h0 = 0)
    const float* bias   = (const float*)d_in[4];  // [256]
    float* out = (float*)d_out;                   // [4,1024,1,64] fp32

    lstm_first_step_kernel<<<GRID_, BLOCK_, 0, stream>>>(tokens, emb, kern, bias, out);
}